// Round 1
// baseline (190.461 us; speedup 1.0000x reference)
//
#include <hip/hip_runtime.h>

// Problem constants (from setup_inputs): B=16, C=128, H=128, W=128, K=256, S=1024
#define B_ 16
#define C_ 128
#define H_ 128
#define W_ 128
#define K_ 256
#define S_ 1024
#define BK_   (B_ * K_)        // 4096 (b,k) rows
#define PAIRS 4                // (b,k) rows per block
#define NBLK  (BK_ / PAIRS)    // 1024 blocks

// One block per 4 consecutive (b,k) rows (same b: 256 % 4 == 0).
// Stage 4x128 gathered channel values in LDS (2 independent loads/thread ->
// 2x MLP on the latency-critical strided gather), then each thread computes
// one float4 of interpolated outputs per pair vs a float4 target load.
// Block-reduce, one contention-free store of (partial, active_count).
__global__ __launch_bounds__(256) void maskloss_main(
    const float* __restrict__ shape,
    const int*   __restrict__ mask,
    const int*   __restrict__ ind,
    const float* __restrict__ target,
    float*       __restrict__ partial,   // [NBLK]
    int*         __restrict__ counts)    // [NBLK]
{
    const int blk = blockIdx.x;
    const int bk0 = blk * PAIRS;
    const int b   = bk0 >> 8;            // K_ == 256
    const int tid = threadIdx.x;

    __shared__ int   sMask[PAIRS];
    __shared__ int   sInd[PAIRS];
    __shared__ float pred[PAIRS][C_];    // 2 KB

    if (tid < PAIRS) {
        sMask[tid] = mask[bk0 + tid];
        sInd[tid]  = ind[bk0 + tid];
    }
    __syncthreads();

    const int nact = sMask[0] + sMask[1] + sMask[2] + sMask[3];
    if (nact == 0) {                     // all 4 rows masked out (p = 1/16)
        if (tid == 0) { partial[blk] = 0.f; counts[blk] = 0; }
        return;
    }

    // Gather: slot = p*128 + c for p in [0,4), c in [0,128). 2 loads/thread,
    // independent -> both in flight. Each wave covers one pair (uniform branch).
    const size_t planeB = (size_t)b * (C_ * H_ * W_);
#pragma unroll
    for (int j = 0; j < (PAIRS * C_) / 256; ++j) {   // 2 iterations
        const int slot = tid + j * 256;
        const int p    = slot >> 7;
        const int c    = slot & (C_ - 1);
        if (sMask[p])
            pred[p][c] = shape[planeB + (size_t)c * (H_ * W_) + sInd[p]];
    }
    __syncthreads();

    float acc = 0.f;
#pragma unroll
    for (int p = 0; p < PAIRS; ++p) {
        if (!sMask[p]) continue;         // block-uniform branch
        const float4 t =
            reinterpret_cast<const float4*>(target + (size_t)(bk0 + p) * S_)[tid];
        const float* pr = pred[p];
        float v[4];
#pragma unroll
        for (int j = 0; j < 4; ++j) {
            const int s = 4 * tid + j;
            // pp = (s + 0.5) * (C/S) - 0.5 = s*0.125 - 0.4375 (exact in fp32)
            float pp = fmaf((float)s, 0.125f, -0.4375f);
            pp = fminf(fmaxf(pp, 0.f), 127.f);
            const int   lo = (int)pp;
            const float w  = pp - (float)lo;
            const int   hi = min(lo + 1, C_ - 1);
            v[j] = pr[lo] * (1.f - w) + pr[hi] * w;   // same expr as verified kernel
        }
        acc += fabsf(v[0] - t.x) + fabsf(v[1] - t.y)
             + fabsf(v[2] - t.z) + fabsf(v[3] - t.w);
    }

    // wave (64-lane) shuffle reduce, then cross-wave via LDS
    for (int off = 32; off > 0; off >>= 1)
        acc += __shfl_down(acc, off, 64);
    __shared__ float wsum[4];
    if ((tid & 63) == 0) wsum[tid >> 6] = acc;
    __syncthreads();
    if (tid == 0) {
        partial[blk] = (wsum[0] + wsum[1]) + (wsum[2] + wsum[3]);
        counts[blk]  = nact;
    }
}

// Single block: reduce 1024 partials (double accum) + 1024 counts, write scalar.
__global__ __launch_bounds__(1024) void maskloss_final(
    const float* __restrict__ partial,
    const int*   __restrict__ counts,
    float*       __restrict__ out)
{
    const int tid = threadIdx.x;         // NBLK == 1024 == blockDim
    double lsum = (double)partial[tid];
    int    csum = counts[tid];
    for (int off = 32; off > 0; off >>= 1) {
        lsum += __shfl_down(lsum, off, 64);
        csum += __shfl_down(csum, off, 64);
    }
    __shared__ double lw[16];
    __shared__ int    cw[16];
    if ((tid & 63) == 0) { lw[tid >> 6] = lsum; cw[tid >> 6] = csum; }
    __syncthreads();
    if (tid == 0) {
        double L = 0.0; int Cn = 0;
#pragma unroll
        for (int i = 0; i < 16; ++i) { L += lw[i]; Cn += cw[i]; }
        out[0] = (float)(L / ((double)Cn * (double)S_ + 1e-4));
    }
}

extern "C" void kernel_launch(void* const* d_in, const int* in_sizes, int n_in,
                              void* d_out, int out_size, void* d_ws, size_t ws_size,
                              hipStream_t stream) {
    const float* shape  = (const float*)d_in[0];
    // d_in[1] = size (int32 scalar, == 1024, hardcoded)
    // d_in[2] = saliency (unused by the reference)
    const int*   mask   = (const int*)d_in[3];
    const int*   ind    = (const int*)d_in[4];
    const float* target = (const float*)d_in[5];
    float*       out    = (float*)d_out;

    float* partial = (float*)d_ws;            // 1024 floats = 4 KB
    int*   counts  = (int*)d_ws + NBLK;       // 1024 ints   = 4 KB

    maskloss_main<<<NBLK, 256, 0, stream>>>(shape, mask, ind, target, partial, counts);
    maskloss_final<<<1, 1024, 0, stream>>>(partial, counts, out);
}